// Round 1
// baseline (116.444 us; speedup 1.0000x reference)
//
#include <hip/hip_runtime.h>
#include <stdint.h>

#define NROWS 4096
#define DIM   512
#define BK    32
#define TILE  128
#define NBLK  32            // NROWS / TILE
#define NPAIR 528           // NBLK*(NBLK+1)/2
#define KSTEPS (DIM / BK)   // 16

typedef float f32x4 __attribute__((ext_vector_type(4)));
typedef short s16x8 __attribute__((ext_vector_type(8)));

// workspace layout (bytes)
#define OFF_XB   0u
#define OFF_SQ   (NROWS * DIM * 2u)          // 4,194,304
#define OFF_LAB  (OFF_SQ + NROWS * 4u)       // + 16 KB
#define OFF_ACC  (OFF_LAB + NROWS * 4u)      // + 16 KB

__device__ __forceinline__ unsigned short f2bf(float f) {
  unsigned u = __float_as_uint(f);
  return (unsigned short)((u + 0x7FFFu + ((u >> 16) & 1u)) >> 16);
}

typedef __attribute__((address_space(1))) unsigned int glb_uint;
typedef __attribute__((address_space(3))) unsigned int lds_uint;

__device__ __forceinline__ void gl2lds16(const void* g, void* l) {
  __builtin_amdgcn_global_load_lds(
      (glb_uint*)(uintptr_t)g,
      (lds_uint*)(unsigned int)(uintptr_t)l,
      16, 0, 0);
}

// ---------------- prep: fp32 -> bf16, sq rows (fp32 exact), labels -> i32, zero accum
__global__ __launch_bounds__(256) void prep_kernel(
    const float* __restrict__ X, const long long* __restrict__ lab,
    unsigned short* __restrict__ Xb, float* __restrict__ sq,
    int* __restrict__ labi, float* __restrict__ accum)
{
  int t = threadIdx.x;
  int gid = blockIdx.x * 256 + t;
  if (gid < 4) accum[gid] = 0.0f;               // sum1, sum2, cnt(bits), done-counter
  if (gid < NROWS) labi[gid] = (int)lab[gid];

  int wave = t >> 6, lane = t & 63;
  int row = blockIdx.x * 4 + wave;              // 1024 blocks * 4 rows
  const float4* Xr = (const float4*)(X + (size_t)row * DIM);
  float4 a = Xr[lane * 2];
  float4 b = Xr[lane * 2 + 1];

  uint4 pk;
  pk.x = (unsigned)f2bf(a.x) | ((unsigned)f2bf(a.y) << 16);
  pk.y = (unsigned)f2bf(a.z) | ((unsigned)f2bf(a.w) << 16);
  pk.z = (unsigned)f2bf(b.x) | ((unsigned)f2bf(b.y) << 16);
  pk.w = (unsigned)f2bf(b.z) | ((unsigned)f2bf(b.w) << 16);
  *(uint4*)(Xb + (size_t)row * DIM + lane * 8) = pk;

  float s = a.x*a.x + a.y*a.y + a.z*a.z + a.w*a.w
          + b.x*b.x + b.y*b.y + b.z*b.z + b.w*b.w;
  #pragma unroll
  for (int off = 32; off; off >>= 1) s += __shfl_down(s, off, 64);
  if (lane == 0) sq[row] = s;
}

// ---------------- main: symmetric tiled X*X^T, 2-phase double-buffered pipeline,
//                  chunk-plane LDS layout (conflict-free ds_read_b128), fused epilogue+finalize.
//
// LDS layout per buffer: 4 "k-sub planes" of [128 rows][16 B]:
//   slot s (16B units, s in [0,512)):  ksub = s>>7, row = s&127.
// global_load_lds dest stays LINEAR (t*16B); the permutation is applied on the
// per-lane GLOBAL source address instead (rule #21: both-sides-or-neither).
// Fragment read addr = quad*2048 + row*16 bytes -> any aligned 8-lane group
// (8 consecutive rows) covers all 32 banks: conflict-free.
__global__ __launch_bounds__(256) void pair_kernel(
    const unsigned short* __restrict__ Xb, const float* __restrict__ sq,
    const int* __restrict__ labi, const float* __restrict__ marginp,
    float* __restrict__ accum, float* __restrict__ out)
{
  __shared__ unsigned short As[2][4096];   // 2 x 8 KB
  __shared__ unsigned short Bs[2][4096];   // 2 x 8 KB
  __shared__ float sRow[TILE], sCol[TILE];
  __shared__ int   lRow[TILE], lCol[TILE];
  __shared__ float rs1[4], rs2[4];
  __shared__ int   rc[4];

  int t = threadIdx.x;

  // linear block -> (bi, bj) with bi <= bj
  int rem = blockIdx.x, bi = 0;
  while (rem >= (NBLK - bi)) { rem -= (NBLK - bi); bi++; }
  int bj = bi + rem;

  int wave = t >> 6, lane = t & 63;
  int quad = lane >> 4, ml = lane & 15;
  int waveRow = (wave >> 1) * 64, waveCol = (wave & 1) * 64;

  // ---- hoisted epilogue loads: issue NOW, they drain at the first barrier
  float margin = *marginp;
  float sqv; int lbv;
  {
    int u = t & 127;
    int base = (t < TILE ? bi : bj) * TILE + u;
    sqv = sq[base];
    lbv = labi[base];
  }

  // ---- staging source mapping (chunk-plane):
  // LDS slot s covered by instruction pair: inst0 -> s = t         (ksub = t>>7,   row = t&127)
  //                                         inst1 -> s = 256 + t   (ksub = 2+(t>>7), row = t&127)
  const int rr = t & 127;
  const int ch = t >> 7;                    // 0 or 1
  const size_t gA = (size_t)(bi * TILE + rr) * DIM + ch * 8;
  const size_t gB = (size_t)(bj * TILE + rr) * DIM + ch * 8;

  f32x4 acc[4][4] = {};

  #define STAGE(buf, kt)                                                      \
    do {                                                                      \
      size_t ko = (size_t)(kt) * BK;                                          \
      gl2lds16(Xb + gA + ko,      (void*)(&As[(buf)][t * 8]));                \
      gl2lds16(Xb + gA + ko + 16, (void*)(&As[(buf)][2048 + t * 8]));         \
      gl2lds16(Xb + gB + ko,      (void*)(&Bs[(buf)][t * 8]));                \
      gl2lds16(Xb + gB + ko + 16, (void*)(&Bs[(buf)][2048 + t * 8]));         \
    } while (0)

  #define COMPUTE(buf)                                                        \
    do {                                                                      \
      const s16x8* Ap = (const s16x8*)As[(buf)];                              \
      const s16x8* Bp = (const s16x8*)Bs[(buf)];                              \
      s16x8 af[4], bfr[4];                                                    \
      _Pragma("unroll")                                                       \
      for (int r = 0; r < 4; ++r)                                             \
        af[r] = Ap[quad * 128 + waveRow + r * 16 + ml];                       \
      _Pragma("unroll")                                                       \
      for (int c = 0; c < 4; ++c)                                             \
        bfr[c] = Bp[quad * 128 + waveCol + c * 16 + ml];                      \
      _Pragma("unroll")                                                       \
      for (int r = 0; r < 4; ++r)                                             \
        _Pragma("unroll")                                                     \
        for (int c = 0; c < 4; ++c)                                           \
          acc[r][c] = __builtin_amdgcn_mfma_f32_16x16x32_bf16(                \
              af[r], bfr[c], acc[r][c], 0, 0, 0);                             \
    } while (0)

  // ---- 2-phase pipeline: one barrier per K-step; prefetch stays in flight
  // across the compute (compiler drains vmcnt(0) at the NEXT barrier, which is
  // exactly where the prefetched buffer is first consumed).
  STAGE(0, 0);
  int cur = 0;
  for (int kt = 0; kt < KSTEPS - 1; ++kt) {
    __syncthreads();              // buf[cur] staged; prev reads of buf[cur^1] done
    STAGE(cur ^ 1, kt + 1);       // issue next tile's loads (in flight during MFMA)
    COMPUTE(cur);
    cur ^= 1;
  }
  __syncthreads();
  COMPUTE(cur);                   // last tile, no prefetch

  // ---- epilogue: stage sq/label tiles from registers
  if (t < TILE) { sRow[t] = sqv; lRow[t] = lbv; }
  else          { sCol[t - TILE] = sqv; lCol[t - TILE] = lbv; }
  __syncthreads();

  float s1 = 0.f, s2 = 0.f;
  int cnt = 0;
  #pragma unroll
  for (int c = 0; c < 4; ++c) {
    int col = waveCol + c * 16 + ml;
    float sqc = sCol[col];
    int lc = lCol[col];
    #pragma unroll
    for (int r = 0; r < 4; ++r) {
      int rbase = waveRow + r * 16 + quad * 4;   // C/D layout: row=(lane>>4)*4+reg, col=lane&15
      #pragma unroll
      for (int i = 0; i < 4; ++i) {
        int row = rbase + i;
        float d = sRow[row] + sqc - 2.0f * acc[r][c][i];
        d = fmaxf(d, 0.0f);
        if (lRow[row] == lc) { s1 += d; cnt++; }
        else                 { s2 += fmaxf(margin - d, 0.0f); }
      }
    }
  }

  #pragma unroll
  for (int off = 32; off; off >>= 1) {
    s1  += __shfl_down(s1, off, 64);
    s2  += __shfl_down(s2, off, 64);
    cnt += __shfl_down(cnt, off, 64);
  }
  if (lane == 0) { rs1[wave] = s1; rs2[wave] = s2; rc[wave] = cnt; }
  __syncthreads();
  if (t == 0) {
    float f = (bi == bj) ? 1.f : 2.f;
    float S1 = 0.f, S2 = 0.f;
    int C = 0;
    for (int w = 0; w < 4; ++w) { S1 += rs1[w]; S2 += rs2[w]; C += rc[w]; }
    atomicAdd(&accum[0], S1 * f);
    atomicAdd(&accum[1], S2 * f);
    atomicAdd((unsigned*)accum + 2, (unsigned)C * (unsigned)((bi == bj) ? 1 : 2));
    __threadfence();
    // fused finalize: last block to finish computes the scalar output
    unsigned done = atomicAdd((unsigned*)accum + 3, 1u);
    if (done == NPAIR - 1) {
      __threadfence();
      float S1f = atomicAdd(&accum[0], 0.0f);         // device-scope coherent read
      float S2f = atomicAdd(&accum[1], 0.0f);
      unsigned c1 = atomicAdd((unsigned*)accum + 2, 0u);
      double zn1 = (double)c1;
      double zn2 = (double)NROWS * (double)NROWS - zn1;
      out[0] = (float)(0.5 * ((double)S1f / zn1 + (double)S2f / zn2));
    }
  }
  #undef STAGE
  #undef COMPUTE
}

extern "C" void kernel_launch(void* const* d_in, const int* in_sizes, int n_in,
                              void* d_out, int out_size, void* d_ws, size_t ws_size,
                              hipStream_t stream) {
  const float*     X      = (const float*)d_in[0];
  const long long* lab    = (const long long*)d_in[1];
  const float*     margin = (const float*)d_in[2];
  float*           out    = (float*)d_out;

  char* ws = (char*)d_ws;
  unsigned short* Xb   = (unsigned short*)(ws + OFF_XB);
  float*          sq   = (float*)(ws + OFF_SQ);
  int*            labi = (int*)(ws + OFF_LAB);
  float*          accum= (float*)(ws + OFF_ACC);

  prep_kernel<<<NROWS / 4, 256, 0, stream>>>(X, lab, Xb, sq, labi, accum);
  pair_kernel<<<NPAIR, 256, 0, stream>>>(Xb, sq, labi, margin, accum, out);
}

// Round 2
// 100.970 us; speedup vs baseline: 1.1533x; 1.1533x over previous
//
#include <hip/hip_runtime.h>
#include <stdint.h>

#define NROWS 4096
#define DIM   512
#define BK    32
#define TILE  128
#define NBLK  32            // NROWS / TILE
#define NPAIR 528           // NBLK*(NBLK+1)/2
#define KSTEPS (DIM / BK)   // 16

typedef float f32x4 __attribute__((ext_vector_type(4)));
typedef short s16x8 __attribute__((ext_vector_type(8)));

// workspace layout (bytes)
#define OFF_XB   0u
#define OFF_SQ   (NROWS * DIM * 2u)          // 4,194,304
#define OFF_LAB  (OFF_SQ + NROWS * 4u)       // + 16 KB
#define OFF_ACC  (OFF_LAB + NROWS * 4u)      // + 16 KB

__device__ __forceinline__ unsigned short f2bf(float f) {
  unsigned u = __float_as_uint(f);
  return (unsigned short)((u + 0x7FFFu + ((u >> 16) & 1u)) >> 16);
}

typedef __attribute__((address_space(1))) unsigned int glb_uint;
typedef __attribute__((address_space(3))) unsigned int lds_uint;

__device__ __forceinline__ void gl2lds16(const void* g, void* l) {
  __builtin_amdgcn_global_load_lds(
      (glb_uint*)(uintptr_t)g,
      (lds_uint*)(unsigned int)(uintptr_t)l,
      16, 0, 0);
}

// ---------------- prep: fp32 -> bf16, sq rows (fp32 exact), labels -> i32, zero accum
__global__ __launch_bounds__(256) void prep_kernel(
    const float* __restrict__ X, const long long* __restrict__ lab,
    unsigned short* __restrict__ Xb, float* __restrict__ sq,
    int* __restrict__ labi, float* __restrict__ accum)
{
  int t = threadIdx.x;
  int gid = blockIdx.x * 256 + t;
  if (gid < 4) accum[gid] = 0.0f;               // sum1, sum2, cnt(bits), done-counter
  if (gid < NROWS) labi[gid] = (int)lab[gid];

  int wave = t >> 6, lane = t & 63;
  int row = blockIdx.x * 4 + wave;              // 1024 blocks * 4 rows
  const float4* Xr = (const float4*)(X + (size_t)row * DIM);
  float4 a = Xr[lane * 2];
  float4 b = Xr[lane * 2 + 1];

  uint4 pk;
  pk.x = (unsigned)f2bf(a.x) | ((unsigned)f2bf(a.y) << 16);
  pk.y = (unsigned)f2bf(a.z) | ((unsigned)f2bf(a.w) << 16);
  pk.z = (unsigned)f2bf(b.x) | ((unsigned)f2bf(b.y) << 16);
  pk.w = (unsigned)f2bf(b.z) | ((unsigned)f2bf(b.w) << 16);
  *(uint4*)(Xb + (size_t)row * DIM + lane * 8) = pk;

  float s = a.x*a.x + a.y*a.y + a.z*a.z + a.w*a.w
          + b.x*b.x + b.y*b.y + b.z*b.z + b.w*b.w;
  #pragma unroll
  for (int off = 32; off; off >>= 1) s += __shfl_down(s, off, 64);
  if (lane == 0) sq[row] = s;
}

// ---------------- main: symmetric tiled X*X^T
// 512 threads (8 waves, 2x4 wave grid, 64x32 output per wave) for 16 waves/CU.
// Coalesced staging IDENTICAL to the proven round-0 pattern (4 lanes share one
// 64B line); conflict-free fragment reads via an XOR chunk swizzle that only
// permutes lanes WITHIN each 64B line on the global side (coalescing intact):
//   LDS slot (row, ch) holds global chunk ch ^ ((row>>1)&3)
//   read of global chunk q of row -> slot row*4 + (q ^ ((row>>1)&3))
// 2-phase double-buffered pipeline: one barrier per K-step, prefetch in flight
// across the MFMA block. Fused loss epilogue + last-block finalize.
__global__ __launch_bounds__(512) void pair_kernel(
    const unsigned short* __restrict__ Xb, const float* __restrict__ sq,
    const int* __restrict__ labi, const float* __restrict__ marginp,
    float* __restrict__ accum, float* __restrict__ out)
{
  __shared__ unsigned short As[2][TILE * BK];   // 2 x 8 KB
  __shared__ unsigned short Bs[2][TILE * BK];   // 2 x 8 KB
  __shared__ float sRow[TILE], sCol[TILE];
  __shared__ int   lRow[TILE], lCol[TILE];
  __shared__ float rs1[8], rs2[8];
  __shared__ int   rc[8];

  int t = threadIdx.x;

  // linear block -> (bi, bj) with bi <= bj
  int rem = blockIdx.x, bi = 0;
  while (rem >= (NBLK - bi)) { rem -= (NBLK - bi); bi++; }
  int bj = bi + rem;

  int wave = t >> 6, lane = t & 63;
  int quad = lane >> 4, ml = lane & 15;
  int waveRow = (wave >> 2) * 64;               // 0 or 64
  int waveCol = (wave & 3) * 32;                // 0, 32, 64, 96

  // ---- hoisted epilogue loads: issue NOW, latency hidden under the K-loop
  float margin = *marginp;
  float sqv = 0.f; int lbv = 0;
  if (t < 2 * TILE) {
    int u = t & 127;
    int base = (t < TILE ? bi : bj) * TILE + u;
    sqv = sq[base];
    lbv = labi[base];
  }

  // ---- staging: thread t owns LDS slot t (16B) = (row = t>>2, chunk = t&3).
  // Global source chunk is XOR-swizzled within the row's 64B group:
  const int rr = t >> 2;                        // 0..127
  const int cg = (t & 3) ^ ((t >> 3) & 3);      // swizzled chunk, same 64B line
  const size_t gA = (size_t)(bi * TILE + rr) * DIM + cg * 8;
  const size_t gB = (size_t)(bj * TILE + rr) * DIM + cg * 8;

  // read-side swizzle: (row>>1)&3 == (ml>>1)&3 since all tile bases are mult. of 8
  const int xq = quad ^ ((ml >> 1) & 3);

  f32x4 acc[4][2] = {};

  #define STAGE(buf, kt)                                                      \
    do {                                                                      \
      size_t ko = (size_t)(kt) * BK;                                          \
      gl2lds16(Xb + gA + ko, (void*)(&As[(buf)][t * 8]));                     \
      gl2lds16(Xb + gB + ko, (void*)(&Bs[(buf)][t * 8]));                     \
    } while (0)

  #define COMPUTE(buf)                                                        \
    do {                                                                      \
      const s16x8* Ap = (const s16x8*)As[(buf)];                              \
      const s16x8* Bp = (const s16x8*)Bs[(buf)];                              \
      s16x8 af[4], bfr[2];                                                    \
      _Pragma("unroll")                                                       \
      for (int r = 0; r < 4; ++r)                                             \
        af[r] = Ap[(waveRow + r * 16 + ml) * 4 + xq];                         \
      _Pragma("unroll")                                                       \
      for (int c = 0; c < 2; ++c)                                             \
        bfr[c] = Bp[(waveCol + c * 16 + ml) * 4 + xq];                        \
      _Pragma("unroll")                                                       \
      for (int r = 0; r < 4; ++r)                                             \
        _Pragma("unroll")                                                     \
        for (int c = 0; c < 2; ++c)                                           \
          acc[r][c] = __builtin_amdgcn_mfma_f32_16x16x32_bf16(                \
              af[r], bfr[c], acc[r][c], 0, 0, 0);                             \
    } while (0)

  // ---- 2-phase pipeline: one barrier per K-step
  STAGE(0, 0);
  int cur = 0;
  for (int kt = 0; kt < KSTEPS - 1; ++kt) {
    __syncthreads();              // buf[cur] staged; prev reads of buf[cur^1] done
    STAGE(cur ^ 1, kt + 1);       // next tile's loads fly during the MFMAs below
    COMPUTE(cur);
    cur ^= 1;
  }
  __syncthreads();
  COMPUTE(cur);                   // last tile, no prefetch

  // ---- epilogue: stage sq/label tiles from registers
  if (t < TILE)          { sRow[t] = sqv;        lRow[t] = lbv; }
  else if (t < 2 * TILE) { sCol[t - TILE] = sqv; lCol[t - TILE] = lbv; }
  __syncthreads();

  float s1 = 0.f, s2 = 0.f;
  int cnt = 0;
  #pragma unroll
  for (int c = 0; c < 2; ++c) {
    int col = waveCol + c * 16 + ml;
    float sqc = sCol[col];
    int lc = lCol[col];
    #pragma unroll
    for (int r = 0; r < 4; ++r) {
      int rbase = waveRow + r * 16 + quad * 4;   // C/D layout: row=(lane>>4)*4+reg, col=lane&15
      #pragma unroll
      for (int i = 0; i < 4; ++i) {
        int row = rbase + i;
        float d = sRow[row] + sqc - 2.0f * acc[r][c][i];
        d = fmaxf(d, 0.0f);
        if (lRow[row] == lc) { s1 += d; cnt++; }
        else                 { s2 += fmaxf(margin - d, 0.0f); }
      }
    }
  }

  #pragma unroll
  for (int off = 32; off; off >>= 1) {
    s1  += __shfl_down(s1, off, 64);
    s2  += __shfl_down(s2, off, 64);
    cnt += __shfl_down(cnt, off, 64);
  }
  if (lane == 0) { rs1[wave] = s1; rs2[wave] = s2; rc[wave] = cnt; }
  __syncthreads();
  if (t == 0) {
    float f = (bi == bj) ? 1.f : 2.f;
    float S1 = 0.f, S2 = 0.f;
    int C = 0;
    for (int w = 0; w < 8; ++w) { S1 += rs1[w]; S2 += rs2[w]; C += rc[w]; }
    atomicAdd(&accum[0], S1 * f);
    atomicAdd(&accum[1], S2 * f);
    atomicAdd((unsigned*)accum + 2, (unsigned)C * (unsigned)((bi == bj) ? 1 : 2));
    __threadfence();
    // fused finalize: last block to finish computes the scalar output
    unsigned done = atomicAdd((unsigned*)accum + 3, 1u);
    if (done == NPAIR - 1) {
      __threadfence();
      float S1f = atomicAdd(&accum[0], 0.0f);         // device-scope coherent read
      float S2f = atomicAdd(&accum[1], 0.0f);
      unsigned c1 = atomicAdd((unsigned*)accum + 2, 0u);
      double zn1 = (double)c1;
      double zn2 = (double)NROWS * (double)NROWS - zn1;
      out[0] = (float)(0.5 * ((double)S1f / zn1 + (double)S2f / zn2));
    }
  }
  #undef STAGE
  #undef COMPUTE
}

extern "C" void kernel_launch(void* const* d_in, const int* in_sizes, int n_in,
                              void* d_out, int out_size, void* d_ws, size_t ws_size,
                              hipStream_t stream) {
  const float*     X      = (const float*)d_in[0];
  const long long* lab    = (const long long*)d_in[1];
  const float*     margin = (const float*)d_in[2];
  float*           out    = (float*)d_out;

  char* ws = (char*)d_ws;
  unsigned short* Xb   = (unsigned short*)(ws + OFF_XB);
  float*          sq   = (float*)(ws + OFF_SQ);
  int*            labi = (int*)(ws + OFF_LAB);
  float*          accum= (float*)(ws + OFF_ACC);

  prep_kernel<<<NROWS / 4, 256, 0, stream>>>(X, lab, Xb, sq, labi, accum);
  pair_kernel<<<NPAIR, 512, 0, stream>>>(Xb, sq, labi, margin, accum, out);
}